// Round 7
// baseline (164.178 us; speedup 1.0000x reference)
//
#include <hip/hip_runtime.h>

// Problem constants (B=2, L=16, D=4, K=2, N_IN=8, N_OUT=8, NC=3)
#define NSITES (2 * 16 * 16 * 16 * 16)          // 131072 sites
// W:     site-stride 72  floats (8 ch * 3*3), base 288 B (16B aligned)
// U_PT:  site-stride 180 floats (4 mu * 5 ik * 3*3)
// omega: flat [i][j][mu][ik] = i*160 + j*20 + mu*5 + ik  (1280 floats)
// out:   site-stride 72 floats
//
// Decomposition (R6): 8 threads/site = (jh, mu); each thread sandwiches its
// own 4 W channels, exchanges M with partner (lane^4), mixes into its own
// 4 output channels, mu-reduce via shfl_xor(1,2), mu==0 lanes store.
// R7: JIT per-channel W consumption with ping-pong prefetch (Wf[2][12],
// compile-time parity) + depth-1 U prefetch -> hide global-load latency
// under the sandwich/mix FMAs while staying under the 128-VGPR cliff.

#define OM_MU_STRIDE 328   // [mu][ik][j][i], mu-pad: 5*8*8=320 -> 328

__device__ __forceinline__ void loadU9(float* __restrict__ U,
                                       const float* __restrict__ p) {
#pragma unroll
    for (int e = 0; e < 9; ++e) U[e] = p[e];
}

// load channel t (floats t*9 .. t*9+8 of a 36-float half) as 3 float4s
template <int T>
__device__ __forceinline__ void loadWch(float* __restrict__ dst,
                                        const float4* __restrict__ base) {
    constexpr int q0 = (T * 9) >> 2;
#pragma unroll
    for (int q = 0; q < 3; ++q) {
        const float4 v = base[q0 + q];
        dst[q * 4 + 0] = v.x; dst[q * 4 + 1] = v.y;
        dst[q * 4 + 2] = v.z; dst[q * 4 + 3] = v.w;
    }
}

__global__ __launch_bounds__(256) void lconv_kernel(
    const float* __restrict__ W, const float* __restrict__ U_PT,
    const float* __restrict__ omega, float* __restrict__ out)
{
    __shared__ float s_om[4 * OM_MU_STRIDE];
    for (int t = threadIdx.x; t < 1280; t += 256) {
        const int i  = t / 160;
        const int r  = t - i * 160;
        const int j  = r / 20;
        const int r2 = r - j * 20;
        const int m  = r2 / 5;
        const int ik = r2 - m * 5;
        s_om[m * OM_MU_STRIDE + ik * 64 + j * 8 + i] = omega[t];
    }
    __syncthreads();

    // XCD-aware bijective swizzle: 4096 blocks, 8 XCDs, 512-block chunks.
    const int bid = ((int)blockIdx.x & 7) * ((int)gridDim.x >> 3)
                  + ((int)blockIdx.x >> 3);
    const int idx = bid * 256 + (int)threadIdx.x;
    const int s   = idx >> 3;         // site (32 consecutive sites per block)
    const int jh  = (idx >> 2) & 1;   // j-half AND i-half of this thread
    const int mu  = idx & 3;          // axis
    const int sh  = 12 - 4 * mu;      // bit position of x_mu in s
    const int x   = (s >> sh) & 15;

    const float* __restrict__ Ub  = U_PT + (size_t)s * 180 + mu * 45;
    const float* __restrict__ omt = s_om + mu * OM_MU_STRIDE + jh * 4;
    const int jown8 = jh * 32;          // (jh*4)*8
    const int jpar8 = (jh ^ 1) * 32;

    float acc[4][9];
#pragma unroll
    for (int i = 0; i < 4; ++i)
#pragma unroll
        for (int e = 0; e < 9; ++e) acc[i][e] = 0.0f;

    // ---- prologue: W-channel-0 of ik=0 and U of ik=0 in flight ----
    const float4* Wp_c = reinterpret_cast<const float4*>(
        W + (size_t)(s + ((((x - 2 + 16) & 15) - x) << sh)) * 72 + jh * 36);
    float Wf[2][12];
    loadWch<0>(Wf[0], Wp_c);
    float U[9];
    loadU9(U, Ub);

#pragma unroll 1
    for (int ik = 0; ik < 5; ++ik) {
        // next-ik pointers (clamped at the end; harmless redundant prefetch)
        const int ikn = (ik < 4) ? ik + 1 : ik;
        const int kn  = ikn - 2;
        const float4* Wp_n = reinterpret_cast<const float4*>(
            W + (size_t)(s + ((((x + kn + 16) & 15) - x) << sh)) * 72 + jh * 36);
        float Un[9];
        loadU9(Un, Ub + ikn * 9);

#pragma unroll
        for (int t = 0; t < 4; ++t) {
            const int p   = t & 1;
            const int off = (t * 9) & 3;
            // prefetch next channel (t+1 of this ik, or channel 0 of next ik)
            if (t == 0)      loadWch<1>(Wf[p ^ 1], Wp_c);
            else if (t == 1) loadWch<2>(Wf[p ^ 1], Wp_c);
            else if (t == 2) loadWch<3>(Wf[p ^ 1], Wp_c);
            else             loadWch<0>(Wf[p ^ 1], Wp_n);

            const float* __restrict__ Wc = Wf[p] + off;

            // sandwich M = U * W_{jh*4+t} * U^T
            float M[9];
#pragma unroll
            for (int a = 0; a < 3; ++a) {
                const float uw0 = fmaf(U[a * 3 + 0], Wc[0],
                                  fmaf(U[a * 3 + 1], Wc[3],
                                       U[a * 3 + 2] * Wc[6]));
                const float uw1 = fmaf(U[a * 3 + 0], Wc[1],
                                  fmaf(U[a * 3 + 1], Wc[4],
                                       U[a * 3 + 2] * Wc[7]));
                const float uw2 = fmaf(U[a * 3 + 0], Wc[2],
                                  fmaf(U[a * 3 + 1], Wc[5],
                                       U[a * 3 + 2] * Wc[8]));
#pragma unroll
                for (int b2 = 0; b2 < 3; ++b2)
                    M[a * 3 + b2] = fmaf(uw0, U[b2 * 3 + 0],
                                    fmaf(uw1, U[b2 * 3 + 1],
                                         uw2 * U[b2 * 3 + 2]));
            }

            // omega (LDS, conflict-free, 8-lane broadcast)
            const float4 wo = *reinterpret_cast<const float4*>(
                                  omt + ik * 64 + jown8 + t * 8);
            const float4 wp = *reinterpret_cast<const float4*>(
                                  omt + ik * 64 + jpar8 + t * 8);
            const float wov[4] = {wo.x, wo.y, wo.z, wo.w};
            const float wpv[4] = {wp.x, wp.y, wp.z, wp.w};

            // mix own M and partner's M (exchanged via shfl_xor lane^4)
#pragma unroll
            for (int e = 0; e < 9; ++e) {
                const float mp = __shfl_xor(M[e], 4);
#pragma unroll
                for (int ii = 0; ii < 4; ++ii)
                    acc[ii][e] = fmaf(wov[ii], M[e],
                                 fmaf(wpv[ii], mp, acc[ii][e]));
            }
        }

        Wp_c = Wp_n;
#pragma unroll
        for (int e = 0; e < 9; ++e) U[e] = Un[e];
    }

    // reduce the 4 mu-partials within each mu-quad
#pragma unroll
    for (int i = 0; i < 4; ++i)
#pragma unroll
        for (int e = 0; e < 9; ++e) {
            float v = acc[i][e];
            v += __shfl_xor(v, 1);
            v += __shfl_xor(v, 2);
            acc[i][e] = v;
        }

    // mu==0 lanes (2 per site) store their 36-float half-block (9 float4)
    if (mu == 0) {
        float4* __restrict__ o4 =
            reinterpret_cast<float4*>(out + (size_t)s * 72 + jh * 36);
#pragma unroll
        for (int q = 0; q < 9; ++q) {
            const int f = q * 4;
            o4[q] = make_float4(acc[(f + 0) / 9][(f + 0) % 9],
                                acc[(f + 1) / 9][(f + 1) % 9],
                                acc[(f + 2) / 9][(f + 2) % 9],
                                acc[(f + 3) / 9][(f + 3) % 9]);
        }
    }
}

extern "C" void kernel_launch(void* const* d_in, const int* in_sizes, int n_in,
                              void* d_out, int out_size, void* d_ws, size_t ws_size,
                              hipStream_t stream) {
    const float* W   = (const float*)d_in[0];
    const float* U   = (const float*)d_in[1];
    const float* om  = (const float*)d_in[2];
    float*       out = (float*)d_out;

    const int block = 256;
    const int grid  = (NSITES * 8) / block;   // 4096 blocks
    hipLaunchKernelGGL(lconv_kernel, dim3(grid), dim3(block), 0, stream,
                       W, U, om, out);
}

// Round 8
// 142.786 us; speedup vs baseline: 1.1498x; 1.1498x over previous
//
#include <hip/hip_runtime.h>

// Problem constants (B=2, L=16, D=4, K=2, N_IN=8, N_OUT=8, NC=3)
#define NSITES (2 * 16 * 16 * 16 * 16)          // 131072 sites
// W:     site-stride 72  floats (8 ch * 3*3), base 288 B (16B aligned)
// U_PT:  site-stride 180 floats (4 mu * 5 ik * 3*3)
// omega: flat [i][j][mu][ik] = i*160 + j*20 + mu*5 + ik  (1280 floats)
// out:   site-stride 72 floats
//
// R8: block-level coalesced W staging through LDS.
//   Block = 32 consecutive sites (local = x2lsb*16 + x3). Central W range
//   staged once; per ik (k!=0) the three shifted regions for mu=0,1,2 are
//   staged with pre-applied shift (region[mu][lsite] = W[site(lsite)+delta]).
//   mu=3 neighbors wrap inside the central range (read central at shifted
//   lsite). All staging loads are lane-linear float4 -> fully coalesced;
//   consume is LDS reads (padded stride 76 + region skew -> <=2-way).
//   Compute/threading identical to R6 (8 thr/site = (jh,mu), partner-M via
//   shfl_xor(4), mu-reduce via shfl_xor(1,2)). Depth-1 U register prefetch.

#define OM_OFF     0            // omega: [mu][ik][j][i], mu-stride 328
#define CENT_OFF   1316         // central region (skewed start)
#define REG_OFF    3752         // shifted regions base
#define REG_STRIDE 2436         // 32*76 + 4 skew
#define SITE_F     76           // padded floats per site in LDS
#define LDS_FLOATS (REG_OFF + 3 * REG_STRIDE)   // 11060 -> 44240 B

__device__ __forceinline__ void loadU9(float* __restrict__ U,
                                       const float* __restrict__ p) {
#pragma unroll
    for (int e = 0; e < 9; ++e) U[e] = p[e];
}

__global__ __launch_bounds__(256) void lconv_kernel(
    const float* __restrict__ W, const float* __restrict__ U_PT,
    const float* __restrict__ omega, float* __restrict__ out)
{
    __shared__ float lds[LDS_FLOATS];
    const int tid = threadIdx.x;

    // omega -> [mu][ik][j][i]
    for (int t = tid; t < 1280; t += 256) {
        const int i  = t / 160;
        const int r  = t - i * 160;
        const int j  = r / 20;
        const int r2 = r - j * 20;
        const int m  = r2 / 5;
        const int ik = r2 - m * 5;
        lds[OM_OFF + m * 328 + ik * 64 + j * 8 + i] = omega[t];
    }

    // XCD-aware bijective swizzle: 4096 blocks, 8 XCDs, 512-block chunks.
    const int bid = ((int)blockIdx.x & 7) * ((int)gridDim.x >> 3)
                  + ((int)blockIdx.x >> 3);
    const int s0  = bid * 32;

    // stage central 32-site W range (576 float4, coalesced)
    {
        const float4* __restrict__ W4 =
            reinterpret_cast<const float4*>(W) + (size_t)s0 * 18;
#pragma unroll
        for (int q = 0; q < 3; ++q) {
            const int flat = q * 256 + tid;
            if (flat < 576) {
                const int lsite = flat / 18;
                const int f4    = flat - lsite * 18;
                *reinterpret_cast<float4*>(
                    lds + CENT_OFF + lsite * SITE_F + f4 * 4) =
                    W4[lsite * 18 + f4];
            }
        }
    }

    const int local = tid >> 3;          // 0..31 site local id
    const int s     = s0 + local;
    const int jh    = (tid >> 2) & 1;    // j-half AND i-half
    const int mu    = tid & 3;           // axis
    const int x3    = s & 15;
    const int x2b   = (s >> 4) & 1;

    const int c0 = (s0 >> 12) & 15;      // uniform block coords
    const int c1 = (s0 >> 8) & 15;
    const int c2 = (s0 >> 4) & 15;       // even

    const float* __restrict__ Ub  = U_PT + (size_t)s * 180 + mu * 45;
    const float* __restrict__ omt = lds + OM_OFF + mu * 328 + jh * 4;
    const int jown8 = jh * 32;
    const int jpar8 = (jh ^ 1) * 32;

    float acc[4][9];
#pragma unroll
    for (int i = 0; i < 4; ++i)
#pragma unroll
        for (int e = 0; e < 9; ++e) acc[i][e] = 0.0f;

    float U[9];
    loadU9(U, Ub);                       // ik=0

#pragma unroll 1
    for (int ik = 0; ik < 5; ++ik) {
        const int k   = ik - 2;
        const int ikn = (ik < 4) ? ik + 1 : ik;
        float Un[9];
        loadU9(Un, Ub + ikn * 9);        // depth-1 U prefetch

        if (k != 0) {
            // stage regions mu=0,1,2 with pre-applied shift (1728 float4)
            const int d0  = ((((c0 + k) & 15) - c0) << 12);
            const int d1  = ((((c1 + k) & 15) - c1) << 8);
            const int d2a = ((((c2 + k) & 15) - c2) << 4);
            const int d2b = ((((c2 + 1 + k) & 15) - (c2 + 1)) << 4);
            const float4* __restrict__ W4 =
                reinterpret_cast<const float4*>(W);
#pragma unroll
            for (int q = 0; q < 7; ++q) {
                const int flat = q * 256 + tid;
                if (flat < 1728) {
                    const int r     = flat / 576;
                    const int rem   = flat - r * 576;
                    const int lsite = rem / 18;
                    const int f4    = rem - lsite * 18;
                    const int delta = (r == 0) ? d0
                                    : (r == 1) ? d1
                                    : ((lsite >= 16) ? d2b : d2a);
                    *reinterpret_cast<float4*>(
                        lds + REG_OFF + r * REG_STRIDE
                            + lsite * SITE_F + f4 * 4) =
                        W4[(size_t)(s0 + lsite + delta) * 18 + f4];
                }
            }
        }
        __syncthreads();   // staged data (and omega/central on ik=0) visible

        // ---- consume from LDS ----
        const int  use_cent = (k == 0) || (mu == 3);
        const float* __restrict__ wbase =
            use_cent ? (lds + CENT_OFF) : (lds + REG_OFF + mu * REG_STRIDE);
        const int lb = (mu == 3 && k != 0)
                     ? (((x3 + k) & 15) + x2b * 16) : local;
        const float* __restrict__ Wp = wbase + lb * SITE_F + jh * 36;

        float Wl[36];
#pragma unroll
        for (int q = 0; q < 9; ++q) {
            const float4 v = *reinterpret_cast<const float4*>(Wp + q * 4);
            Wl[q * 4 + 0] = v.x; Wl[q * 4 + 1] = v.y;
            Wl[q * 4 + 2] = v.z; Wl[q * 4 + 3] = v.w;
        }

#pragma unroll
        for (int t = 0; t < 4; ++t) {
            // sandwich M = U * W_{jh*4+t} * U^T
            float M[9];
#pragma unroll
            for (int a = 0; a < 3; ++a) {
                const float uw0 = fmaf(U[a * 3 + 0], Wl[t * 9 + 0],
                                  fmaf(U[a * 3 + 1], Wl[t * 9 + 3],
                                       U[a * 3 + 2] * Wl[t * 9 + 6]));
                const float uw1 = fmaf(U[a * 3 + 0], Wl[t * 9 + 1],
                                  fmaf(U[a * 3 + 1], Wl[t * 9 + 4],
                                       U[a * 3 + 2] * Wl[t * 9 + 7]));
                const float uw2 = fmaf(U[a * 3 + 0], Wl[t * 9 + 2],
                                  fmaf(U[a * 3 + 1], Wl[t * 9 + 5],
                                       U[a * 3 + 2] * Wl[t * 9 + 8]));
#pragma unroll
                for (int b2 = 0; b2 < 3; ++b2)
                    M[a * 3 + b2] = fmaf(uw0, U[b2 * 3 + 0],
                                    fmaf(uw1, U[b2 * 3 + 1],
                                         uw2 * U[b2 * 3 + 2]));
            }

            const float4 wo = *reinterpret_cast<const float4*>(
                                  omt + ik * 64 + jown8 + t * 8);
            const float4 wp = *reinterpret_cast<const float4*>(
                                  omt + ik * 64 + jpar8 + t * 8);
            const float wov[4] = {wo.x, wo.y, wo.z, wo.w};
            const float wpv[4] = {wp.x, wp.y, wp.z, wp.w};

#pragma unroll
            for (int e = 0; e < 9; ++e) {
                const float mp = __shfl_xor(M[e], 4);
#pragma unroll
                for (int ii = 0; ii < 4; ++ii)
                    acc[ii][e] = fmaf(wov[ii], M[e],
                                 fmaf(wpv[ii], mp, acc[ii][e]));
            }
        }
        __syncthreads();   // all consumed before next ik's staging overwrite

#pragma unroll
        for (int e = 0; e < 9; ++e) U[e] = Un[e];
    }

    // reduce the 4 mu-partials within each mu-quad
#pragma unroll
    for (int i = 0; i < 4; ++i)
#pragma unroll
        for (int e = 0; e < 9; ++e) {
            float v = acc[i][e];
            v += __shfl_xor(v, 1);
            v += __shfl_xor(v, 2);
            acc[i][e] = v;
        }

    // mu==0 lanes (2 per site) store their 36-float half-block (9 float4)
    if (mu == 0) {
        float4* __restrict__ o4 =
            reinterpret_cast<float4*>(out + (size_t)s * 72 + jh * 36);
#pragma unroll
        for (int q = 0; q < 9; ++q) {
            const int f = q * 4;
            o4[q] = make_float4(acc[(f + 0) / 9][(f + 0) % 9],
                                acc[(f + 1) / 9][(f + 1) % 9],
                                acc[(f + 2) / 9][(f + 2) % 9],
                                acc[(f + 3) / 9][(f + 3) % 9]);
        }
    }
}

extern "C" void kernel_launch(void* const* d_in, const int* in_sizes, int n_in,
                              void* d_out, int out_size, void* d_ws, size_t ws_size,
                              hipStream_t stream) {
    const float* W   = (const float*)d_in[0];
    const float* U   = (const float*)d_in[1];
    const float* om  = (const float*)d_in[2];
    float*       out = (float*)d_out;

    const int block = 256;
    const int grid  = NSITES / 32;    // 4096 blocks, 32 sites each
    hipLaunchKernelGGL(lconv_kernel, dim3(grid), dim3(block), 0, stream,
                       W, U, om, out);
}

// Round 9
// 111.708 us; speedup vs baseline: 1.4697x; 1.2782x over previous
//
#include <hip/hip_runtime.h>

// Problem constants (B=2, L=16, D=4, K=2, N_IN=8, N_OUT=8, NC=3)
#define NSITES (2 * 16 * 16 * 16 * 16)          // 131072 sites
// W:     site-stride 72  floats (8 ch * 3*3), base 288 B (16B aligned)
// U_PT:  site-stride 180 floats (4 mu * 5 ik * 3*3)
// omega: flat [i][j][mu][ik] = i*160 + j*20 + mu*5 + ik  (1280 floats)
// out:   site-stride 72 floats
//
// R9: block = 32 consecutive sites, 8 thr/site = (jh, mu)  [R6 compute].
//   Staged ONCE per block (one barrier total, no divisions in staging):
//     - U_PT slice  [32][184]  (pad 180->184, <=2-way banks on read)
//     - central W   [32][76]   (serves mu=3 wraps and k=0 for all mu)
//     - omega       [mu][ik][j][i]  (stride 328)
//   mu=0,1,2 k!=0 W reads stay direct-global (R6 path).
//   This kills the U scalar-load request storm (9 dwords/thread/ik at
//   720B stride was ~half the TA traffic) and 25% of W requests, and
//   LDS=38.5KB keeps 4 blocks/CU resident.

#define OM_OFF 0                 // 4*328 = 1312 floats
#define U_OFF  1312              // 32*184 = 5888 floats
#define C_OFF  (1312 + 5888)     // 32*76  = 2432 floats
#define LDS_FLOATS (C_OFF + 2432)   // 9632 floats = 38528 B

__global__ __launch_bounds__(256) void lconv_kernel(
    const float* __restrict__ W, const float* __restrict__ U_PT,
    const float* __restrict__ omega, float* __restrict__ out)
{
    __shared__ float lds[LDS_FLOATS];
    const int tid = threadIdx.x;

    // XCD-aware bijective swizzle: 4096 blocks, 8 XCDs, 512-block chunks.
    const int bid = ((int)blockIdx.x & 7) * ((int)gridDim.x >> 3)
                  + ((int)blockIdx.x >> 3);
    const int s0  = bid * 32;

    // ---- one-time staging (all lane-linear float4, no divisions) ----
    {
        const int site = tid >> 3;       // 0..31
        const int r8   = tid & 7;        // 0..7

        // omega -> [mu][ik][j][i] (1280 floats; divisions ok, once)
        for (int t = tid; t < 1280; t += 256) {
            const int i  = t / 160;
            const int r  = t - i * 160;
            const int j  = r / 20;
            const int r2 = r - j * 20;
            const int m  = r2 / 5;
            const int ik = r2 - m * 5;
            lds[OM_OFF + m * 328 + ik * 64 + j * 8 + i] = omega[t];
        }

        // U slice: 32 sites x 45 float4 -> [site][184]
        const float4* __restrict__ U4 =
            reinterpret_cast<const float4*>(U_PT) + (size_t)s0 * 45;
#pragma unroll
        for (int st = 0; st < 6; ++st) {
            const int f4r = st * 8 + r8;
            if (st < 5 || f4r < 45) {
                *reinterpret_cast<float4*>(
                    lds + U_OFF + site * 184 + f4r * 4) =
                    U4[site * 45 + f4r];
            }
        }

        // central W: 32 sites x 18 float4 -> [site][76]
        const float4* __restrict__ W4 =
            reinterpret_cast<const float4*>(W) + (size_t)s0 * 18;
#pragma unroll
        for (int st = 0; st < 3; ++st) {
            const int f4r = st * 8 + r8;
            if (st < 2 || f4r < 18) {
                *reinterpret_cast<float4*>(
                    lds + C_OFF + site * 76 + f4r * 4) =
                    W4[site * 18 + f4r];
            }
        }
    }
    __syncthreads();

    const int local = tid >> 3;          // 0..31 site local id
    const int s     = s0 + local;
    const int jh    = (tid >> 2) & 1;    // j-half AND i-half
    const int mu    = tid & 3;           // axis
    const int sh    = 12 - 4 * mu;       // bit position of x_mu in s
    const int x     = (s >> sh) & 15;

    const float* __restrict__ Ul  = lds + U_OFF + local * 184 + mu * 45;
    const float* __restrict__ omt = lds + OM_OFF + mu * 328 + jh * 4;
    const int jown8 = jh * 32;
    const int jpar8 = (jh ^ 1) * 32;

    float acc[4][9];
#pragma unroll
    for (int i = 0; i < 4; ++i)
#pragma unroll
        for (int e = 0; e < 9; ++e) acc[i][e] = 0.0f;

#pragma unroll 1
    for (int ik = 0; ik < 5; ++ik) {
        const int k = ik - 2;

        // U from LDS (scalar ds_reads, <=2-way banks, cheap)
        float U[9];
#pragma unroll
        for (int e = 0; e < 9; ++e) U[e] = Ul[ik * 9 + e];

        // W fragment: central LDS for (k==0 or mu==3), else direct global
        const int  lbw     = ((local + k) & 15) | (local & 16); // x3 wrap
        const bool use_lds = (k == 0) || (mu == 3);

        float Wl[36];
        if (use_lds) {
            const float4* __restrict__ Wp = reinterpret_cast<const float4*>(
                lds + C_OFF + lbw * 76 + jh * 36);
#pragma unroll
            for (int q = 0; q < 9; ++q) {
                const float4 v = Wp[q];
                Wl[q * 4 + 0] = v.x; Wl[q * 4 + 1] = v.y;
                Wl[q * 4 + 2] = v.z; Wl[q * 4 + 3] = v.w;
            }
        } else {
            const int ns = s + ((((x + k + 16) & 15) - x) << sh);
            const float4* __restrict__ Wp = reinterpret_cast<const float4*>(
                W + (size_t)ns * 72 + jh * 36);
#pragma unroll
            for (int q = 0; q < 9; ++q) {
                const float4 v = Wp[q];
                Wl[q * 4 + 0] = v.x; Wl[q * 4 + 1] = v.y;
                Wl[q * 4 + 2] = v.z; Wl[q * 4 + 3] = v.w;
            }
        }

#pragma unroll
        for (int t = 0; t < 4; ++t) {
            // sandwich M = U * W_{jh*4+t} * U^T
            float M[9];
#pragma unroll
            for (int a = 0; a < 3; ++a) {
                const float uw0 = fmaf(U[a * 3 + 0], Wl[t * 9 + 0],
                                  fmaf(U[a * 3 + 1], Wl[t * 9 + 3],
                                       U[a * 3 + 2] * Wl[t * 9 + 6]));
                const float uw1 = fmaf(U[a * 3 + 0], Wl[t * 9 + 1],
                                  fmaf(U[a * 3 + 1], Wl[t * 9 + 4],
                                       U[a * 3 + 2] * Wl[t * 9 + 7]));
                const float uw2 = fmaf(U[a * 3 + 0], Wl[t * 9 + 2],
                                  fmaf(U[a * 3 + 1], Wl[t * 9 + 5],
                                       U[a * 3 + 2] * Wl[t * 9 + 8]));
#pragma unroll
                for (int b2 = 0; b2 < 3; ++b2)
                    M[a * 3 + b2] = fmaf(uw0, U[b2 * 3 + 0],
                                    fmaf(uw1, U[b2 * 3 + 1],
                                         uw2 * U[b2 * 3 + 2]));
            }

            // omega (LDS, conflict-free, 8-lane broadcast)
            const float4 wo = *reinterpret_cast<const float4*>(
                                  omt + ik * 64 + jown8 + t * 8);
            const float4 wp = *reinterpret_cast<const float4*>(
                                  omt + ik * 64 + jpar8 + t * 8);
            const float wov[4] = {wo.x, wo.y, wo.z, wo.w};
            const float wpv[4] = {wp.x, wp.y, wp.z, wp.w};

            // mix own M and partner's M (exchanged via shfl_xor lane^4)
#pragma unroll
            for (int e = 0; e < 9; ++e) {
                const float mp = __shfl_xor(M[e], 4);
#pragma unroll
                for (int ii = 0; ii < 4; ++ii)
                    acc[ii][e] = fmaf(wov[ii], M[e],
                                 fmaf(wpv[ii], mp, acc[ii][e]));
            }
        }
    }

    // reduce the 4 mu-partials within each mu-quad
#pragma unroll
    for (int i = 0; i < 4; ++i)
#pragma unroll
        for (int e = 0; e < 9; ++e) {
            float v = acc[i][e];
            v += __shfl_xor(v, 1);
            v += __shfl_xor(v, 2);
            acc[i][e] = v;
        }

    // mu==0 lanes (2 per site) store their 36-float half-block (9 float4)
    if (mu == 0) {
        float4* __restrict__ o4 =
            reinterpret_cast<float4*>(out + (size_t)s * 72 + jh * 36);
#pragma unroll
        for (int q = 0; q < 9; ++q) {
            const int f = q * 4;
            o4[q] = make_float4(acc[(f + 0) / 9][(f + 0) % 9],
                                acc[(f + 1) / 9][(f + 1) % 9],
                                acc[(f + 2) / 9][(f + 2) % 9],
                                acc[(f + 3) / 9][(f + 3) % 9]);
        }
    }
}

extern "C" void kernel_launch(void* const* d_in, const int* in_sizes, int n_in,
                              void* d_out, int out_size, void* d_ws, size_t ws_size,
                              hipStream_t stream) {
    const float* W   = (const float*)d_in[0];
    const float* U   = (const float*)d_in[1];
    const float* om  = (const float*)d_in[2];
    float*       out = (float*)d_out;

    const int block = 256;
    const int grid  = NSITES / 32;    // 4096 blocks, 32 sites each
    hipLaunchKernelGGL(lconv_kernel, dim3(grid), dim3(block), 0, stream,
                       W, U, om, out);
}

// Round 10
// 109.307 us; speedup vs baseline: 1.5020x; 1.0220x over previous
//
#include <hip/hip_runtime.h>

// Problem constants (B=2, L=16, D=4, K=2, N_IN=8, N_OUT=8, NC=3)
#define NSITES (2 * 16 * 16 * 16 * 16)          // 131072 sites
// W:     site-stride 72  floats (8 ch * 3*3), base 288 B (16B aligned)
// U_PT:  site-stride 180 floats (4 mu * 5 ik * 3*3)
// omega: flat [i][j][mu][ik] = i*160 + j*20 + mu*5 + ik  (1280 floats)
// out:   site-stride 72 floats
//
// R10: R9 minus central-W staging.
//   Block = 32 consecutive sites, 8 thr/site = (jh, mu) [R6 compute].
//   Staged once (one barrier): U_PT slice [32][184] + omega [mu][ik][j][i].
//   LDS = 28.8 KB -> 5 blocks/CU (was 4 at 38.9 KB).  All W reads are
//   direct-global and BRANCH-FREE (uniform neighbor formula; a wave's
//   addresses are contiguous 8-site runs per mu -> decent coalescing,
//   halo reuse via L1/L2).

#define OM_OFF 0                 // 4*328 = 1312 floats
#define U_OFF  1312              // 32*184 = 5888 floats
#define LDS_FLOATS (U_OFF + 5888)   // 7200 floats = 28800 B

__global__ __launch_bounds__(256) void lconv_kernel(
    const float* __restrict__ W, const float* __restrict__ U_PT,
    const float* __restrict__ omega, float* __restrict__ out)
{
    __shared__ float lds[LDS_FLOATS];
    const int tid = threadIdx.x;

    // XCD-aware bijective swizzle: 4096 blocks, 8 XCDs, 512-block chunks.
    const int bid = ((int)blockIdx.x & 7) * ((int)gridDim.x >> 3)
                  + ((int)blockIdx.x >> 3);
    const int s0  = bid * 32;

    // ---- one-time staging ----
    {
        const int site = tid >> 3;       // 0..31
        const int r8   = tid & 7;        // 0..7

        // omega -> [mu][ik][j][i] (1280 floats; divisions ok, once)
        for (int t = tid; t < 1280; t += 256) {
            const int i  = t / 160;
            const int r  = t - i * 160;
            const int j  = r / 20;
            const int r2 = r - j * 20;
            const int m  = r2 / 5;
            const int ik = r2 - m * 5;
            lds[OM_OFF + m * 328 + ik * 64 + j * 8 + i] = omega[t];
        }

        // U slice: 32 sites x 45 float4 -> [site][184] (lane-linear, coalesced)
        const float4* __restrict__ U4 =
            reinterpret_cast<const float4*>(U_PT) + (size_t)s0 * 45;
#pragma unroll
        for (int st = 0; st < 6; ++st) {
            const int f4r = st * 8 + r8;
            if (st < 5 || f4r < 45) {
                *reinterpret_cast<float4*>(
                    lds + U_OFF + site * 184 + f4r * 4) =
                    U4[site * 45 + f4r];
            }
        }
    }
    __syncthreads();

    const int local = tid >> 3;          // 0..31 site local id
    const int s     = s0 + local;
    const int jh    = (tid >> 2) & 1;    // j-half AND i-half
    const int mu    = tid & 3;           // axis
    const int sh    = 12 - 4 * mu;       // bit position of x_mu in s
    const int x     = (s >> sh) & 15;

    const float* __restrict__ Ul  = lds + U_OFF + local * 184 + mu * 45;
    const float* __restrict__ omt = lds + OM_OFF + mu * 328 + jh * 4;
    const int jown8 = jh * 32;
    const int jpar8 = (jh ^ 1) * 32;

    float acc[4][9];
#pragma unroll
    for (int i = 0; i < 4; ++i)
#pragma unroll
        for (int e = 0; e < 9; ++e) acc[i][e] = 0.0f;

#pragma unroll 1
    for (int ik = 0; ik < 5; ++ik) {
        const int k = ik - 2;

        // neighbor site along mu (uniform, branch-free)
        const int ns = s + ((((x + k + 16) & 15) - x) << sh);
        const float4* __restrict__ Wp =
            reinterpret_cast<const float4*>(W + (size_t)ns * 72 + jh * 36);

        // issue W loads first, then U from LDS (overlap vmem with ds)
        float Wl[36];
#pragma unroll
        for (int q = 0; q < 9; ++q) {
            const float4 v = Wp[q];
            Wl[q * 4 + 0] = v.x; Wl[q * 4 + 1] = v.y;
            Wl[q * 4 + 2] = v.z; Wl[q * 4 + 3] = v.w;
        }

        float U[9];
#pragma unroll
        for (int e = 0; e < 9; ++e) U[e] = Ul[ik * 9 + e];

#pragma unroll
        for (int t = 0; t < 4; ++t) {
            // sandwich M = U * W_{jh*4+t} * U^T
            float M[9];
#pragma unroll
            for (int a = 0; a < 3; ++a) {
                const float uw0 = fmaf(U[a * 3 + 0], Wl[t * 9 + 0],
                                  fmaf(U[a * 3 + 1], Wl[t * 9 + 3],
                                       U[a * 3 + 2] * Wl[t * 9 + 6]));
                const float uw1 = fmaf(U[a * 3 + 0], Wl[t * 9 + 1],
                                  fmaf(U[a * 3 + 1], Wl[t * 9 + 4],
                                       U[a * 3 + 2] * Wl[t * 9 + 7]));
                const float uw2 = fmaf(U[a * 3 + 0], Wl[t * 9 + 2],
                                  fmaf(U[a * 3 + 1], Wl[t * 9 + 5],
                                       U[a * 3 + 2] * Wl[t * 9 + 8]));
#pragma unroll
                for (int b2 = 0; b2 < 3; ++b2)
                    M[a * 3 + b2] = fmaf(uw0, U[b2 * 3 + 0],
                                    fmaf(uw1, U[b2 * 3 + 1],
                                         uw2 * U[b2 * 3 + 2]));
            }

            // omega (LDS, conflict-free, 8-lane broadcast)
            const float4 wo = *reinterpret_cast<const float4*>(
                                  omt + ik * 64 + jown8 + t * 8);
            const float4 wp = *reinterpret_cast<const float4*>(
                                  omt + ik * 64 + jpar8 + t * 8);
            const float wov[4] = {wo.x, wo.y, wo.z, wo.w};
            const float wpv[4] = {wp.x, wp.y, wp.z, wp.w};

            // mix own M and partner's M (exchanged via shfl_xor lane^4)
#pragma unroll
            for (int e = 0; e < 9; ++e) {
                const float mp = __shfl_xor(M[e], 4);
#pragma unroll
                for (int ii = 0; ii < 4; ++ii)
                    acc[ii][e] = fmaf(wov[ii], M[e],
                                 fmaf(wpv[ii], mp, acc[ii][e]));
            }
        }
    }

    // reduce the 4 mu-partials within each mu-quad
#pragma unroll
    for (int i = 0; i < 4; ++i)
#pragma unroll
        for (int e = 0; e < 9; ++e) {
            float v = acc[i][e];
            v += __shfl_xor(v, 1);
            v += __shfl_xor(v, 2);
            acc[i][e] = v;
        }

    // mu==0 lanes (2 per site) store their 36-float half-block (9 float4)
    if (mu == 0) {
        float4* __restrict__ o4 =
            reinterpret_cast<float4*>(out + (size_t)s * 72 + jh * 36);
#pragma unroll
        for (int q = 0; q < 9; ++q) {
            const int f = q * 4;
            o4[q] = make_float4(acc[(f + 0) / 9][(f + 0) % 9],
                                acc[(f + 1) / 9][(f + 1) % 9],
                                acc[(f + 2) / 9][(f + 2) % 9],
                                acc[(f + 3) / 9][(f + 3) % 9]);
        }
    }
}

extern "C" void kernel_launch(void* const* d_in, const int* in_sizes, int n_in,
                              void* d_out, int out_size, void* d_ws, size_t ws_size,
                              hipStream_t stream) {
    const float* W   = (const float*)d_in[0];
    const float* U   = (const float*)d_in[1];
    const float* om  = (const float*)d_in[2];
    float*       out = (float*)d_out;

    const int block = 256;
    const int grid  = NSITES / 32;    // 4096 blocks, 32 sites each
    hipLaunchKernelGGL(lconv_kernel, dim3(grid), dim3(block), 0, stream,
                       W, U, om, out);
}